// Round 1
// 247.954 us; speedup vs baseline: 1.0444x; 1.0444x over previous
//
#include <hip/hip_runtime.h>
#include <hip/hip_bf16.h>

// GraphSAGE 2-layer forward — CSR-gather + bf16 MFMA GEMMs.
//   zl = x@W1l, zr = x@W1r     (bf16 MFMA, SPLIT packed arrays [n,64])
//   h  = sigmoid(csr_mean(zl) + zr + b1)        (h bf16 [n,64])
//   ql = h@W2l, qr = h@W2r     (split packed [n,40])
//   out = csr_mean(ql) + qr + b2                (fp32 [n,40])
//
// R1 changes vs 259µs baseline:
//  - CSR build: single atomic pass. hist stores rank[e]=atomicAdd(deg[dst],1);
//    fill_csr is atomic-free (csr[off[dst]+rank[e]]=src). cursor removed.
//  - gemm1 fused with hist into one launch (hist latency hides under MFMA).
//  - agg: dword gathers (2 bf16/lane, 2 edges per wave-load), shfl_xor combine.
//  - deg zeroing folded into prep_w (no memset dispatch). 13 -> 9 dispatches.

#define N_FEAT 128
#define HID 64
#define NCLS 40

typedef short short8 __attribute__((ext_vector_type(8)));
typedef float floatx4 __attribute__((ext_vector_type(4)));

static __device__ __forceinline__ short f2bf(float x) {
    __hip_bfloat16 h = __float2bfloat16(x);
    return __builtin_bit_cast(short, h);
}
static __device__ __forceinline__ float bf2f(unsigned short u) {
    unsigned int v = ((unsigned int)u) << 16;
    return __builtin_bit_cast(float, v);
}

// ---------------------------------------------------------------------------
// Weight prep (transpose + cvt to bf16, concatenated [l|r]) + zero deg.
// wt1[n=0..127][k=0..127], wt2[n=0..79][k=0..63]
// ---------------------------------------------------------------------------
__global__ void prep_w(const float* __restrict__ W1l, const float* __restrict__ W1r,
                       const float* __restrict__ W2l, const float* __restrict__ W2r,
                       unsigned short* __restrict__ wt1,
                       unsigned short* __restrict__ wt2,
                       int* __restrict__ deg, int n) {
    int i = blockIdx.x * blockDim.x + threadIdx.x;
    if (i < 128 * 128) {
        int nn = i >> 7, k = i & 127;
        float v = (nn < 64) ? W1l[k * 64 + nn] : W1r[k * 64 + (nn - 64)];
        wt1[nn * 128 + k] = (unsigned short)f2bf(v);
    } else if (i < 128 * 128 + 80 * 64) {
        int j = i - 128 * 128;
        int nn = j >> 6, k = j & 63;
        float v = (nn < 40) ? W2l[k * 40 + nn] : W2r[k * 40 + (nn - 40)];
        wt2[nn * 64 + k] = (unsigned short)f2bf(v);
    }
    if (i < n) deg[i] = 0;
}

// ---------------------------------------------------------------------------
// Scans (CSR offsets from deg histogram)
// ---------------------------------------------------------------------------
__global__ void scan_blocks(const int* __restrict__ deg, int* __restrict__ off,
                            int* __restrict__ bsums, int n) {
    __shared__ int lds[256];
    const int b = blockIdx.x, t = threadIdx.x;
    const int base = b * 2048 + t * 8;
    int v[8], s = 0;
#pragma unroll
    for (int i = 0; i < 8; ++i) {
        int idx = base + i;
        v[i] = (idx < n) ? deg[idx] : 0;
        s += v[i];
    }
    lds[t] = s;
    __syncthreads();
    for (int o = 1; o < 256; o <<= 1) {
        int y = (t >= o) ? lds[t - o] : 0;
        __syncthreads();
        lds[t] += y;
        __syncthreads();
    }
    int run = (t == 0) ? 0 : lds[t - 1];
#pragma unroll
    for (int i = 0; i < 8; ++i) {
        run += v[i];
        int idx = base + i;
        if (idx < n) off[idx + 1] = run;
    }
    if (t == 255) bsums[b] = lds[255];
    if (b == 0 && t == 0) off[0] = 0;
}

// parallel exclusive scan of block sums (nb <= 256)
__global__ void scan_top(int* __restrict__ bsums, int nb) {
    __shared__ int lds[256];
    const int t = threadIdx.x;
    lds[t] = (t < nb) ? bsums[t] : 0;
    __syncthreads();
    for (int o = 1; o < 256; o <<= 1) {
        int y = (t >= o) ? lds[t - o] : 0;
        __syncthreads();
        lds[t] += y;
        __syncthreads();
    }
    if (t < nb) bsums[t] = (t == 0) ? 0 : lds[t - 1];
}

__global__ void scan_add(int* __restrict__ off, const int* __restrict__ bsums,
                         int n) {
    int i = blockIdx.x * blockDim.x + threadIdx.x;
    if (i < n) off[i + 1] += bsums[i >> 11];
}

// atomic-free CSR fill: slot = off[dst] + rank (rank captured during hist)
__global__ void fill_csr(const int* __restrict__ ei, const int* __restrict__ off,
                         const int* __restrict__ rank, int* __restrict__ csr,
                         int ne) {
    int e = blockIdx.x * blockDim.x + threadIdx.x;
    if (e < ne) {
        int d = ei[ne + e];
        csr[off[d] + rank[e]] = ei[e];
    }
}

// ---------------------------------------------------------------------------
// MFMA GEMM body: cols [0,MH) -> Zl packed [n,MH], cols [MH,2MH) -> Zr [n,MH].
// Block = 256 thr (4 waves), 64 rows/block; K fully staged in LDS (+8 pad).
// ---------------------------------------------------------------------------
template <int K, int MH, bool AF32>
static __device__ __forceinline__ void gemm_body(
    const void* __restrict__ Ain, const unsigned short* __restrict__ Wt,
    unsigned short* __restrict__ Zl, unsigned short* __restrict__ Zr, int n,
    int bid) {
    constexpr int M = 2 * MH;
    constexpr int LDA = K + 8;
    constexpr int MT = (M + 15) / 16;
    constexpr int KS = K / 32;
    constexpr int QROW = K / 8;
    __shared__ __align__(16) short At[64 * LDA];
    __shared__ __align__(16) short Bt[M * LDA];

    const int t = threadIdx.x;
    const int nodeBase = bid * 64;

    for (int q = t; q < 64 * QROW; q += 256) {
        int row = q / QROW;
        int k0 = (q % QROW) * 8;
        int node = nodeBase + row;
        short8 s = {0, 0, 0, 0, 0, 0, 0, 0};
        if (node < n) {
            if (AF32) {
                const float* A = (const float*)Ain + (size_t)node * K + k0;
                float4 v0 = *(const float4*)A;
                float4 v1 = *(const float4*)(A + 4);
                s[0] = f2bf(v0.x); s[1] = f2bf(v0.y);
                s[2] = f2bf(v0.z); s[3] = f2bf(v0.w);
                s[4] = f2bf(v1.x); s[5] = f2bf(v1.y);
                s[6] = f2bf(v1.z); s[7] = f2bf(v1.w);
            } else {
                s = *(const short8*)((const short*)Ain + (size_t)node * K + k0);
            }
        }
        *(short8*)&At[row * LDA + k0] = s;
    }
    for (int q = t; q < M * QROW; q += 256) {
        int row = q / QROW;
        int k0 = (q % QROW) * 8;
        *(short8*)&Bt[row * LDA + k0] =
            *(const short8*)((const short*)Wt + (size_t)row * K + k0);
    }
    __syncthreads();

    const int wave = t >> 6;
    const int lane = t & 63;
    const int m0 = wave * 16;
    const int fl = lane & 15;
    const int quad = lane >> 4;

    floatx4 acc[MT];
#pragma unroll
    for (int nt = 0; nt < MT; ++nt) acc[nt] = (floatx4){0.f, 0.f, 0.f, 0.f};

#pragma unroll
    for (int ks = 0; ks < KS; ++ks) {
        const int kb = ks * 32 + quad * 8;
        short8 a = *(const short8*)&At[(m0 + fl) * LDA + kb];
#pragma unroll
        for (int nt = 0; nt < MT; ++nt) {
            short8 b = *(const short8*)&Bt[(nt * 16 + fl) * LDA + kb];
            acc[nt] = __builtin_amdgcn_mfma_f32_16x16x32_bf16(a, b, acc[nt], 0, 0, 0);
        }
    }

    // epilogue: D[row=quad*4+r][col=nt*16+fl] -> split Zl/Zr (packed MH)
#pragma unroll
    for (int nt = 0; nt < MT; ++nt) {
        const int col = nt * 16 + fl;
#pragma unroll
        for (int r = 0; r < 4; ++r) {
            int node = nodeBase + m0 + quad * 4 + r;
            if (node < n) {
                unsigned short v = (unsigned short)f2bf(acc[nt][r]);
                if (col < MH)
                    Zl[(size_t)node * MH + col] = v;
                else
                    Zr[(size_t)node * MH + (col - MH)] = v;
            }
        }
    }
}

// Fused layer-1 GEMM + degree histogram (rank-recording).
// Blocks [0,hblocks): hist (latency-bound, no LDS use) — launched first so the
// long pole starts immediately; blocks [hblocks, ...): GEMM tiles.
__global__ __launch_bounds__(256) void gemm_l1_hist(
    const float* __restrict__ x, const unsigned short* __restrict__ wt1,
    unsigned short* __restrict__ zl, unsigned short* __restrict__ zr, int n,
    const int* __restrict__ ei, int* __restrict__ deg, int* __restrict__ rank,
    int ne, int hblocks) {
    if ((int)blockIdx.x < hblocks) {
        int e = blockIdx.x * blockDim.x + threadIdx.x;
        if (e < ne) rank[e] = atomicAdd(&deg[ei[ne + e]], 1);
        return;
    }
    gemm_body<N_FEAT, HID, true>(x, wt1, zl, zr, n, blockIdx.x - hblocks);
}

template <int K, int MH, bool AF32>
__global__ __launch_bounds__(256) void gemm_mfma(
    const void* __restrict__ Ain, const unsigned short* __restrict__ Wt,
    unsigned short* __restrict__ Zl, unsigned short* __restrict__ Zr, int n) {
    gemm_body<K, MH, AF32>(Ain, Wt, Zl, Zr, n, blockIdx.x);
}

// ---------------------------------------------------------------------------
// CSR aggregate + epilogue. One wave per node; each lane owns a dword
// (2 bf16 feats); half-wave 0 takes even edges, half-wave 1 odd edges
// (2 row-gathers per load instruction). Combine via shfl_xor(32).
// ---------------------------------------------------------------------------
template <int F, bool SIG, bool OUTBF>
__global__ void agg_kernel(const unsigned short* __restrict__ Zl,
                           const unsigned short* __restrict__ Zr,
                           const int* __restrict__ off,
                           const int* __restrict__ csr,
                           const float* __restrict__ bias,
                           void* __restrict__ out, int n) {
    const int node = blockIdx.x * (blockDim.x >> 6) + (threadIdx.x >> 6);
    const int lane = threadIdx.x & 63;
    if (node >= n) return;
    const int start = off[node];
    const int end = off[node + 1];
    constexpr int FD = F / 2;  // dwords per row
    const int half = lane >> 5;
    const int col = lane & 31;
    float ax = 0.f, ay = 0.f;
    for (int e = start; e < end; e += 8) {
        int idx[8];
#pragma unroll
        for (int i = 0; i < 8; ++i) {
            int ee = (e + i < end) ? (e + i) : (end - 1);
            idx[i] = csr[ee];
        }
#pragma unroll
        for (int i = 0; i < 4; ++i) {
            unsigned int d = 0;
            if (col < FD)
                d = *(const unsigned int*)(Zl + (size_t)idx[2 * i + half] * F +
                                           2 * col);
            float w = (e + 2 * i + half < end) ? 1.f : 0.f;
            ax += w * bf2f((unsigned short)(d & 0xffffu));
            ay += w * bf2f((unsigned short)(d >> 16));
        }
    }
    // combine the two half-wave partial sums
    ax += __shfl_xor(ax, 32);
    ay += __shfl_xor(ay, 32);
    if (lane < FD) {
        float inv = 1.0f / fmaxf((float)(end - start), 1.0f);
        unsigned int z =
            *(const unsigned int*)(Zr + (size_t)node * F + 2 * lane);
        float2 bb = ((const float2*)bias)[lane];
        float rx = ax * inv + bf2f((unsigned short)(z & 0xffffu)) + bb.x;
        float ry = ay * inv + bf2f((unsigned short)(z >> 16)) + bb.y;
        if (SIG) {
            rx = 1.0f / (1.0f + __expf(-rx));
            ry = 1.0f / (1.0f + __expf(-ry));
        }
        if (OUTBF) {
            unsigned int p = (unsigned int)(unsigned short)f2bf(rx) |
                             ((unsigned int)(unsigned short)f2bf(ry) << 16);
            ((unsigned int*)out)[(size_t)node * FD + lane] = p;
        } else {
            float2 o = {rx, ry};
            ((float2*)out)[(size_t)node * FD + lane] = o;
        }
    }
}

// ---------------------------------------------------------------------------
extern "C" void kernel_launch(void* const* d_in, const int* in_sizes, int n_in,
                              void* d_out, int out_size, void* d_ws,
                              size_t ws_size, hipStream_t stream) {
    const float* x = (const float*)d_in[0];
    const int* ei = (const int*)d_in[1];
    const float* W1l = (const float*)d_in[2];
    const float* b1 = (const float*)d_in[3];
    const float* W1r = (const float*)d_in[4];
    const float* W2l = (const float*)d_in[5];
    const float* b2 = (const float*)d_in[6];
    const float* W2r = (const float*)d_in[7];
    float* out = (float*)d_out;

    const int n = in_sizes[0] / N_FEAT;  // 100000
    const int ne = in_sizes[1] / 2;      // 600000

    // ws: zl1|zr1 [n*64] | h [n*64] | zl2|zr2 [n*40] | wt1 | wt2 | ints
    unsigned short* zl1 = (unsigned short*)d_ws;
    unsigned short* zr1 = zl1 + (size_t)n * HID;
    unsigned short* h = zr1 + (size_t)n * HID;
    unsigned short* zl2 = h + (size_t)n * HID;
    unsigned short* zr2 = zl2 + (size_t)n * NCLS;
    unsigned short* wt1 = zr2 + (size_t)n * NCLS;
    unsigned short* wt2 = wt1 + 128 * 128;
    int* deg = (int*)(wt2 + 80 * 64);
    int* off = deg + n;
    int* rank = off + (n + 1);
    int* csr = rank + ne;
    int* bsums = csr + ne;

    const int nb = (n + 2047) / 2048;
    const int hblocks = (ne + 255) / 256;
    const int gblocks = (n + 63) / 64;
    const int ablocks = (n + 3) / 4;
    const int pwork = (128 * 128 + 80 * 64 > n) ? (128 * 128 + 80 * 64) : n;

    // ---- weight prep + deg zero ----
    prep_w<<<(pwork + 255) / 256, 256, 0, stream>>>(W1l, W1r, W2l, W2r, wt1,
                                                    wt2, deg, n);

    // ---- layer-1 GEMM fused with histogram (independent work overlapped) ----
    gemm_l1_hist<<<hblocks + gblocks, 256, 0, stream>>>(
        x, wt1, zl1, zr1, n, ei, deg, rank, ne, hblocks);

    // ---- CSR offsets + atomic-free fill ----
    scan_blocks<<<nb, 256, 0, stream>>>(deg, off, bsums, n);
    scan_top<<<1, 256, 0, stream>>>(bsums, nb);
    scan_add<<<(n + 255) / 256, 256, 0, stream>>>(off, bsums, n);
    fill_csr<<<(ne + 255) / 256, 256, 0, stream>>>(ei, off, rank, csr, ne);

    // ---- layer 1 aggregate ----
    agg_kernel<HID, true, true>
        <<<ablocks, 256, 0, stream>>>(zl1, zr1, off, csr, b1, h, n);

    // ---- layer 2 ----
    gemm_mfma<HID, NCLS, false><<<gblocks, 256, 0, stream>>>(h, wt2, zl2, zr2, n);
    agg_kernel<NCLS, false, false>
        <<<ablocks, 256, 0, stream>>>(zl2, zr2, off, csr, b2, out, n);
}